// Round 1
// baseline (145.203 us; speedup 1.0000x reference)
//
#include <hip/hip_runtime.h>
#include <math.h>

#define HH 2048
#define WW 2048
#define HWFULL (HH*WW)

// ---------------- K1: bilinear align_corners downsample concat(low,med,high) -> (9,128,128)
__global__ __launch_bounds__(256) void k_ds9(const float* __restrict__ low,
                                             const float* __restrict__ med,
                                             const float* __restrict__ high,
                                             float* __restrict__ ds9) {
    int idx = blockIdx.x * 256 + threadIdx.x;        // 9*128*128 = 147456
    int ch = idx >> 14;
    int rem = idx & 16383;
    int oy = rem >> 7, ox = rem & 127;
    const float* base = (ch < 3) ? low : (ch < 6 ? med : high);
    int c = ch % 3;
    const float* p = base + c * HWFULL;
    float ysf = oy * (2047.0f / 127.0f);
    int y0 = (int)ysf; if (y0 > 2047) y0 = 2047;
    int y1 = y0 + 1;   if (y1 > 2047) y1 = 2047;
    float wy = ysf - (float)y0;
    float xsf = ox * (2047.0f / 127.0f);
    int x0 = (int)xsf; if (x0 > 2047) x0 = 2047;
    int x1 = x0 + 1;   if (x1 > 2047) x1 = 2047;
    float wx = xsf - (float)x0;
    float t = p[y0 * WW + x0] * (1.0f - wx) + p[y0 * WW + x1] * wx;
    float b = p[y1 * WW + x0] * (1.0f - wx) + p[y1 * WW + x1] * wx;
    ds9[idx] = t * (1.0f - wy) + b * wy;
}

// ---------------- K2: conv 9->16, 3x3, stride2, pad1, relu: (9,128,128)->(16,64,64)
__global__ __launch_bounds__(256) void k_conv1(const float* __restrict__ in,
                                               const float* __restrict__ w,
                                               const float* __restrict__ b,
                                               float* __restrict__ out) {
    int idx = blockIdx.x * 256 + threadIdx.x;        // 16*64*64 = 65536
    int o = idx >> 12;
    int rem = idx & 4095;
    int oy = rem >> 6, ox = rem & 63;
    float sum = b[o];
    for (int i = 0; i < 9; ++i) {
        const float* wp = w + (o * 9 + i) * 9;
        const float* ip = in + i * 16384;
        #pragma unroll
        for (int ky = 0; ky < 3; ++ky) {
            int iy = 2 * oy - 1 + ky;
            if (iy < 0 || iy > 127) continue;
            #pragma unroll
            for (int kx = 0; kx < 3; ++kx) {
                int ix = 2 * ox - 1 + kx;
                if (ix < 0 || ix > 127) continue;
                sum += wp[ky * 3 + kx] * ip[iy * 128 + ix];
            }
        }
    }
    out[idx] = fmaxf(sum, 0.0f);
}

// ---------------- K3: conv 16->32: (16,64,64)->(32,32,32)
__global__ __launch_bounds__(256) void k_conv2(const float* __restrict__ in,
                                               const float* __restrict__ w,
                                               const float* __restrict__ b,
                                               float* __restrict__ out) {
    int idx = blockIdx.x * 256 + threadIdx.x;        // 32*32*32 = 32768
    int o = idx >> 10;
    int rem = idx & 1023;
    int oy = rem >> 5, ox = rem & 31;
    float sum = b[o];
    for (int i = 0; i < 16; ++i) {
        const float* wp = w + (o * 16 + i) * 9;
        const float* ip = in + i * 4096;
        #pragma unroll
        for (int ky = 0; ky < 3; ++ky) {
            int iy = 2 * oy - 1 + ky;
            if (iy < 0 || iy > 63) continue;
            #pragma unroll
            for (int kx = 0; kx < 3; ++kx) {
                int ix = 2 * ox - 1 + kx;
                if (ix < 0 || ix > 63) continue;
                sum += wp[ky * 3 + kx] * ip[iy * 64 + ix];
            }
        }
    }
    out[idx] = fmaxf(sum, 0.0f);
}

// ---------------- K4: conv 32->64: (32,32,32)->(64,16,16)
__global__ __launch_bounds__(256) void k_conv3(const float* __restrict__ in,
                                               const float* __restrict__ w,
                                               const float* __restrict__ b,
                                               float* __restrict__ out) {
    int idx = blockIdx.x * 256 + threadIdx.x;        // 64*16*16 = 16384
    int o = idx >> 8;
    int rem = idx & 255;
    int oy = rem >> 4, ox = rem & 15;
    float sum = b[o];
    for (int i = 0; i < 32; ++i) {
        const float* wp = w + (o * 32 + i) * 9;
        const float* ip = in + i * 1024;
        #pragma unroll
        for (int ky = 0; ky < 3; ++ky) {
            int iy = 2 * oy - 1 + ky;
            if (iy < 0 || iy > 31) continue;
            #pragma unroll
            for (int kx = 0; kx < 3; ++kx) {
                int ix = 2 * ox - 1 + kx;
                if (ix < 0 || ix > 31) continue;
                sum += wp[ky * 3 + kx] * ip[iy * 32 + ix];
            }
        }
    }
    out[idx] = fmaxf(sum, 0.0f);
}

// ---------------- K5: conv 64->192 1x1 (no act): (64,16,16)->(192,16,16) == bilateral grid
__global__ __launch_bounds__(256) void k_conv4(const float* __restrict__ in,
                                               const float* __restrict__ w,
                                               const float* __restrict__ b,
                                               float* __restrict__ out) {
    int idx = blockIdx.x * 256 + threadIdx.x;        // 192*16*16 = 49152
    int o = idx >> 8;
    int pix = idx & 255;
    float sum = b[o];
    const float* wp = w + o * 64;
    for (int i = 0; i < 64; ++i)
        sum += wp[i] * in[i * 256 + pix];
    out[idx] = sum;
}

// ---------------- K6: guide at 64x64 sample points (4 full-res px each) + trilinear slice
// writes sct[(h*64+w)*16 + c], c<12 (padded stride 16 for aligned float4 reads)
__global__ __launch_bounds__(256) void k_guide_slice(
        const float* __restrict__ low, const float* __restrict__ med,
        const float* __restrict__ high,
        const float* __restrict__ gw1, const float* __restrict__ gb1,
        const float* __restrict__ gamma, const float* __restrict__ beta,
        const float* __restrict__ mean, const float* __restrict__ var,
        const float* __restrict__ gw2, const float* __restrict__ gb2,
        const float* __restrict__ gridvol, float* __restrict__ sct) {
    int idx = blockIdx.x * 256 + threadIdx.x;        // 64*64 = 4096
    int h = idx >> 6, w = idx & 63;

    // --- guide = bilinear(align_corners) downsample of full-res GuideNN output
    float ysf = h * (2047.0f / 63.0f);
    int y0 = (int)ysf; if (y0 > 2047) y0 = 2047;
    int y1 = y0 + 1;   if (y1 > 2047) y1 = 2047;
    float wy = ysf - (float)y0;
    float xsf = w * (2047.0f / 63.0f);
    int x0 = (int)xsf; if (x0 > 2047) x0 = 2047;
    int x1 = x0 + 1;   if (x1 > 2047) x1 = 2047;
    float wx = xsf - (float)x0;

    int yy[2] = { y0, y1 };
    int xx[2] = { x0, x1 };
    float gp[2][2];
    #pragma unroll
    for (int a = 0; a < 2; ++a) {
        #pragma unroll
        for (int bb = 0; bb < 2; ++bb) {
            int pix = yy[a] * WW + xx[bb];
            float i0 = 0.33f * (low[pix]            + med[pix]            + high[pix]);
            float i1 = 0.33f * (low[HWFULL + pix]   + med[HWFULL + pix]   + high[HWFULL + pix]);
            float i2 = 0.33f * (low[2*HWFULL + pix] + med[2*HWFULL + pix] + high[2*HWFULL + pix]);
            float acc = gb2[0];
            for (int k = 0; k < 16; ++k) {
                float t = gb1[k] + gw1[k*3] * i0 + gw1[k*3+1] * i1 + gw1[k*3+2] * i2;
                t = gamma[k] * (t - mean[k]) * (1.0f / sqrtf(var[k] + 1e-5f)) + beta[k];
                t = fmaxf(t, 0.0f);
                acc += gw2[k] * t;
            }
            gp[a][bb] = 1.0f / (1.0f + expf(-acc));
        }
    }
    float guide = (1.0f - wy) * ((1.0f - wx) * gp[0][0] + wx * gp[0][1])
                +         wy  * ((1.0f - wx) * gp[1][0] + wx * gp[1][1]);

    // --- trilinear slice (align_corners=False, zeros padding)
    float hg = h * (2.0f / 63.0f) - 1.0f;
    float wg = w * (2.0f / 63.0f) - 1.0f;
    float ix = ((guide + 1.0f) * 16.0f - 1.0f) * 0.5f;   // W axis (grid x)
    float iy = ((hg    + 1.0f) * 16.0f - 1.0f) * 0.5f;   // H axis (grid y)
    float iz = ((wg    + 1.0f) * 16.0f - 1.0f) * 0.5f;   // D axis (grid z)
    float xf = floorf(ix), yf = floorf(iy), zf = floorf(iz);
    float fx = ix - xf, fy = iy - yf, fz = iz - zf;
    int xi = (int)xf, yi = (int)yf, zi = (int)zf;

    float scv[12];
    #pragma unroll
    for (int c = 0; c < 12; ++c) scv[c] = 0.0f;

    #pragma unroll
    for (int dz = 0; dz < 2; ++dz) {
        int z = zi + dz; float wz = dz ? fz : 1.0f - fz;
        if (z < 0 || z > 15) continue;
        #pragma unroll
        for (int dy = 0; dy < 2; ++dy) {
            int yv = yi + dy; float wyv = dy ? fy : 1.0f - fy;
            if (yv < 0 || yv > 15) continue;
            #pragma unroll
            for (int dx = 0; dx < 2; ++dx) {
                int xv = xi + dx; float wxv = dx ? fx : 1.0f - fx;
                if (xv < 0 || xv > 15) continue;
                float wgt = wz * wyv * wxv;
                int base = z * 256 + yv * 16 + xv;       // within one (16,16,16) block
                #pragma unroll
                for (int c = 0; c < 12; ++c)
                    scv[c] += wgt * gridvol[(c * 16) * 256 + base];
            }
        }
    }
    float* o = sct + idx * 16;
    #pragma unroll
    for (int c = 0; c < 12; ++c) o[c] = scv[c];
}

// ---------------- K7: full-res apply. 4 px/thread, float4 I/O.
__global__ __launch_bounds__(256) void k_apply(
        const float* __restrict__ low, const float* __restrict__ med,
        const float* __restrict__ high, const float* __restrict__ sct,
        float* __restrict__ out) {
    int g = blockIdx.x * 256 + threadIdx.x;    // 2048*2048/4 groups
    int y = g >> 9;
    int x4 = (g & 511) << 2;

    float iyf = y * (63.0f / 2047.0f);
    int y0 = (int)iyf; if (y0 > 63) y0 = 63;
    int y1 = y0 + 1;   if (y1 > 63) y1 = 63;
    float fy = iyf - (float)y0;

    const int HW4 = HWFULL / 4;
    int vi = (y << 9) + (x4 >> 2);
    union F4 { float4 v; float f[4]; };
    F4 l0, l1, l2, m0, m1, m2, h0, h1, h2;
    const float4* Lp = (const float4*)low;
    const float4* Mp = (const float4*)med;
    const float4* Hp = (const float4*)high;
    l0.v = Lp[vi]; l1.v = Lp[vi + HW4]; l2.v = Lp[vi + 2 * HW4];
    m0.v = Mp[vi]; m1.v = Mp[vi + HW4]; m2.v = Mp[vi + 2 * HW4];
    h0.v = Hp[vi]; h1.v = Hp[vi + HW4]; h2.v = Hp[vi + 2 * HW4];

    float img[3][4];
    #pragma unroll
    for (int p = 0; p < 4; ++p) {
        img[0][p] = 0.33f * (l0.f[p] + m0.f[p] + h0.f[p]);
        img[1][p] = 0.33f * (l1.f[p] + m1.f[p] + h1.f[p]);
        img[2][p] = 0.33f * (l2.f[p] + m2.f[p] + h2.f[p]);
    }

    F4 o0, o1, o2;
    int cx0 = -1;
    float a[12], b[12];
    #pragma unroll
    for (int p = 0; p < 4; ++p) {
        int x = x4 + p;
        float ixf = x * (63.0f / 2047.0f);
        int x0 = (int)ixf; if (x0 > 63) x0 = 63;
        int x1 = x0 + 1;   if (x1 > 63) x1 = 63;
        float fx = ixf - (float)x0;
        if (x0 != cx0) {
            cx0 = x0;
            const float* p00 = sct + (y0 * 64 + x0) * 16;
            const float* p01 = sct + (y0 * 64 + x1) * 16;
            const float* p10 = sct + (y1 * 64 + x0) * 16;
            const float* p11 = sct + (y1 * 64 + x1) * 16;
            #pragma unroll
            for (int j = 0; j < 12; ++j) {
                float t = p00[j], bo = p10[j];
                a[j] = t + (bo - t) * fy;
                float t2 = p01[j], b2 = p11[j];
                b[j] = t2 + (b2 - t2) * fy;
            }
        }
        float cf[12];
        #pragma unroll
        for (int j = 0; j < 12; ++j) cf[j] = a[j] + (b[j] - a[j]) * fx;
        o0.f[p] = cf[0] * img[0][p] + cf[1]  * img[1][p] + cf[2]  * img[2][p] + cf[3];
        o1.f[p] = cf[4] * img[0][p] + cf[5]  * img[1][p] + cf[6]  * img[2][p] + cf[7];
        o2.f[p] = cf[8] * img[0][p] + cf[9]  * img[1][p] + cf[10] * img[2][p] + cf[11];
    }
    float4* Op = (float4*)out;
    Op[vi]           = o0.v;
    Op[vi + HW4]     = o1.v;
    Op[vi + 2 * HW4] = o2.v;
}

extern "C" void kernel_launch(void* const* d_in, const int* in_sizes, int n_in,
                              void* d_out, int out_size, void* d_ws, size_t ws_size,
                              hipStream_t stream) {
    const float* low   = (const float*)d_in[0];
    const float* med   = (const float*)d_in[1];
    const float* high  = (const float*)d_in[2];
    const float* w1    = (const float*)d_in[3];
    const float* b1    = (const float*)d_in[4];
    const float* w2    = (const float*)d_in[5];
    const float* b2    = (const float*)d_in[6];
    const float* w3    = (const float*)d_in[7];
    const float* b3    = (const float*)d_in[8];
    const float* w4    = (const float*)d_in[9];
    const float* b4    = (const float*)d_in[10];
    const float* gw1   = (const float*)d_in[11];
    const float* gb1   = (const float*)d_in[12];
    const float* gamma = (const float*)d_in[13];
    const float* beta  = (const float*)d_in[14];
    const float* mean  = (const float*)d_in[15];
    const float* var   = (const float*)d_in[16];
    const float* gw2   = (const float*)d_in[17];
    const float* gb2   = (const float*)d_in[18];
    float* out = (float*)d_out;

    float* ws      = (float*)d_ws;
    float* ds9     = ws;                    //  9*128*128 = 147456
    float* c1      = ds9 + 147456;          // 16*64*64   =  65536
    float* c2v     = c1 + 65536;            // 32*32*32   =  32768
    float* c3v     = c2v + 32768;           // 64*16*16   =  16384
    float* gridvol = c3v + 16384;           // 192*16*16  =  49152
    float* sct     = gridvol + 49152;       // 64*64*16   =  65536 (12 used, pad 16)

    hipLaunchKernelGGL(k_ds9,   dim3(576), dim3(256), 0, stream, low, med, high, ds9);
    hipLaunchKernelGGL(k_conv1, dim3(256), dim3(256), 0, stream, ds9, w1, b1, c1);
    hipLaunchKernelGGL(k_conv2, dim3(128), dim3(256), 0, stream, c1, w2, b2, c2v);
    hipLaunchKernelGGL(k_conv3, dim3(64),  dim3(256), 0, stream, c2v, w3, b3, c3v);
    hipLaunchKernelGGL(k_conv4, dim3(192), dim3(256), 0, stream, c3v, w4, b4, gridvol);
    hipLaunchKernelGGL(k_guide_slice, dim3(16), dim3(256), 0, stream,
                       low, med, high, gw1, gb1, gamma, beta, mean, var, gw2, gb2,
                       gridvol, sct);
    hipLaunchKernelGGL(k_apply, dim3(4096), dim3(256), 0, stream, low, med, high, sct, out);
}